// Round 1
// baseline (257.996 us; speedup 1.0000x reference)
//
#include <hip/hip_runtime.h>
#include <stdint.h>

typedef __bf16 bf16x8 __attribute__((ext_vector_type(8)));
typedef float  f32x4  __attribute__((ext_vector_type(4)));
typedef uint16_t u16;

#define MAT_ELEMS (1024 * 1024)   // elements per 1024x1024 matrix
#define LDK 1024

// ---------- helpers ----------

__device__ __forceinline__ u16 to_bf16(float f) {
  union { float f; uint32_t u; } v; v.f = f;
  uint32_t u = v.u;
  uint32_t r = u + 0x7FFFu + ((u >> 16) & 1u);   // RNE
  return (u16)(r >> 16);
}

__device__ __forceinline__ void gll16(const void* g, void* l) {
  // async global->LDS, 16 bytes per lane; LDS dest is wave-uniform base + lane*16
  __builtin_amdgcn_global_load_lds(
      (__attribute__((address_space(1))) void*)const_cast<void*>(g),
      (__attribute__((address_space(3))) void*)(l),
      16, 0, 0);
}

__device__ __forceinline__ float fast_sigmoid(float x) {
  x = fminf(fmaxf(x, -30.f), 30.f);
  return 1.0f / (1.0f + __expf(-x));
}

__device__ __forceinline__ float fast_tanh(float x) {
  x = fminf(fmaxf(x, -15.f), 15.f);
  float e = __expf(2.0f * x);
  return (e - 1.0f) / (e + 1.0f);
}

// ---------- prep kernels ----------

struct P8  { const float* p[8]; };
struct P10 { const float* p[10]; };
struct B8  { const float* b[8]; };

// cast 8 L matrices f32 -> bf16, same layout (row-major [M][K])
__global__ __launch_bounds__(256) void cast8_kernel(P8 s, u16* __restrict__ dst) {
  const float* src = s.p[blockIdx.y];
  u16* d = dst + ((size_t)blockIdx.y << 20);
  int i = (blockIdx.x * 256 + threadIdx.x) * 4;
  f32x4 v = *reinterpret_cast<const f32x4*>(src + i);
  ushort4 o;
  o.x = to_bf16(v[0]); o.y = to_bf16(v[1]);
  o.z = to_bf16(v[2]); o.w = to_bf16(v[3]);
  *reinterpret_cast<ushort4*>(d + i) = o;
}

// transpose + cast: out[n][k] = in[k][n], f32 -> bf16. 10 matrices: x, h, R0..R7
__global__ __launch_bounds__(256) void transpose_cast_kernel(P10 s, u16* __restrict__ dstbase) {
  __shared__ float tile[32][33];
  const float* src = s.p[blockIdx.z];
  u16* dst = dstbase + ((size_t)blockIdx.z << 20);
  int tx = threadIdx.x & 31;
  int ty = threadIdx.x >> 5;           // 0..7
  int c0 = blockIdx.x * 32;
  int r0 = blockIdx.y * 32;
#pragma unroll
  for (int i = 0; i < 4; ++i)
    tile[ty + i * 8][tx] = src[(size_t)(r0 + ty + i * 8) * 1024 + c0 + tx];
  __syncthreads();
#pragma unroll
  for (int i = 0; i < 4; ++i) {
    int n = c0 + ty + i * 8;           // output row (= original col)
    int k = r0 + tx;                   // output col (= original row)
    dst[(size_t)n * 1024 + k] = to_bf16(tile[tx][ty + i * 8]);
  }
}

// ---------- GEMM core (m97-style 128x128 tile, BK=32, 4 waves) ----------
// A row-major [1024][1024] bf16 (K contiguous); B given TRANSPOSED: BT[n][k] bf16.
// MODE 0: write bf16 out. MODE 1: write f32 out + bias0 + bias1.

template <int MODE>
__device__ __forceinline__ void gemm_body(
    const u16* __restrict__ A0, const u16* __restrict__ A1,
    const u16* __restrict__ B0, const u16* __restrict__ B1,
    int nkt, int kt_split, int row0, int col0,
    u16* __restrict__ outb, float* __restrict__ outf,
    const float* __restrict__ bias0, const float* __restrict__ bias1,
    u16* As, u16* Bs)
{
  const int tid  = threadIdx.x;
  const int lane = tid & 63;
  const int w    = tid >> 6;
  const int wr   = w >> 1;            // 0..1
  const int wc   = w & 1;             // 0..1
  const int r16  = lane & 15;
  const int kg   = lane >> 4;         // 0..3

  f32x4 acc[4][4];
#pragma unroll
  for (int m = 0; m < 4; ++m)
#pragma unroll
    for (int n = 0; n < 4; ++n) {
      f32x4 z = {0.f, 0.f, 0.f, 0.f};
      acc[m][n] = z;
    }

  const int srow = tid >> 2;          // 0..63
  const int skk  = (tid & 3) * 8;     // 0,8,16,24
  u16* lA0 = As + srow * 32 + skk;
  u16* lA1 = As + (srow + 64) * 32 + skk;
  u16* lB0 = Bs + srow * 32 + skk;
  u16* lB1 = Bs + (srow + 64) * 32 + skk;

  for (int kt = 0; kt < nkt; ++kt) {
    const u16* Ak = (kt < kt_split) ? (A0 + kt * 32) : (A1 + (kt - kt_split) * 32);
    const u16* Bk = (kt < kt_split) ? (B0 + kt * 32) : (B1 + (kt - kt_split) * 32);
    __syncthreads();   // previous compute done before overwrite
    gll16(Ak + (size_t)(row0 + srow)      * LDK + skk, lA0);
    gll16(Ak + (size_t)(row0 + srow + 64) * LDK + skk, lA1);
    gll16(Bk + (size_t)(col0 + srow)      * LDK + skk, lB0);
    gll16(Bk + (size_t)(col0 + srow + 64) * LDK + skk, lB1);
    __syncthreads();   // compiler drains vmcnt before barrier

    bf16x8 af[4], bfr[4];
#pragma unroll
    for (int m = 0; m < 4; ++m)
      af[m] = *reinterpret_cast<const bf16x8*>(As + (wr * 64 + m * 16 + r16) * 32 + kg * 8);
#pragma unroll
    for (int n = 0; n < 4; ++n)
      bfr[n] = *reinterpret_cast<const bf16x8*>(Bs + (wc * 64 + n * 16 + r16) * 32 + kg * 8);
#pragma unroll
    for (int m = 0; m < 4; ++m)
#pragma unroll
      for (int n = 0; n < 4; ++n)
        acc[m][n] = __builtin_amdgcn_mfma_f32_16x16x32_bf16(af[m], bfr[n], acc[m][n], 0, 0, 0);
  }

  // epilogue: D layout col = lane&15, row = (lane>>4)*4 + r  [m89-verified]
#pragma unroll
  for (int m = 0; m < 4; ++m) {
#pragma unroll
    for (int r = 0; r < 4; ++r) {
      int row = row0 + wr * 64 + m * 16 + kg * 4 + r;
#pragma unroll
      for (int n = 0; n < 4; ++n) {
        int col = col0 + wc * 64 + n * 16 + r16;
        if (MODE == 0) {
          outb[(size_t)row * 1024 + col] = to_bf16(acc[m][n][r]);
        } else {
          size_t idx = (size_t)row * 1024 + col;
          outf[idx] = acc[m][n][r] + bias0[idx] + bias1[idx];
        }
      }
    }
  }
}

// stage 1: T_g = L_g @ {x|h}   (8 GEMMs, K=1024)
__global__ __launch_bounds__(256) void gemm_stage1_kernel(
    const u16* __restrict__ Lb, const u16* __restrict__ xT,
    const u16* __restrict__ hT, u16* __restrict__ Tbuf)
{
  __shared__ u16 As[128 * 32];
  __shared__ u16 Bs[128 * 32];
  int g = blockIdx.y;
  const u16* A = Lb + ((size_t)g << 20);
  const u16* B = (g & 1) ? hT : xT;
  u16* out = Tbuf + ((size_t)g << 20);
  int row0 = (blockIdx.x >> 3) * 128;
  int col0 = (blockIdx.x & 7) * 128;
  gemm_body<0>(A, A, B, B, 32, 32, row0, col0, out, nullptr, nullptr, nullptr, As, Bs);
}

// stage 2: P_j = T_{2j} @ R_{2j} + T_{2j+1} @ R_{2j+1} + b_{2j} + b_{2j+1}  (K=2048)
__global__ __launch_bounds__(256) void gemm_stage2_kernel(
    const u16* __restrict__ Tbuf, const u16* __restrict__ RT,
    B8 bp, float* __restrict__ P)
{
  __shared__ u16 As[128 * 32];
  __shared__ u16 Bs[128 * 32];
  int j = blockIdx.y;
  const u16* A0 = Tbuf + ((size_t)(2 * j) << 20);
  const u16* B0 = RT   + ((size_t)(2 * j) << 20);
  int row0 = (blockIdx.x >> 3) * 128;
  int col0 = (blockIdx.x & 7) * 128;
  gemm_body<1>(A0, A0 + MAT_ELEMS, B0, B0 + MAT_ELEMS, 64, 32, row0, col0,
               nullptr, P + ((size_t)j << 20), bp.b[2 * j], bp.b[2 * j + 1], As, Bs);
}

// final elementwise LSTM cell
__global__ __launch_bounds__(256) void lstm_cell_kernel(
    const float* __restrict__ P, const float* __restrict__ c, float* __restrict__ out)
{
  int i = (blockIdx.x * 256 + threadIdx.x) * 4;
  f32x4 pi = *reinterpret_cast<const f32x4*>(P + i);
  f32x4 pf = *reinterpret_cast<const f32x4*>(P + MAT_ELEMS + i);
  f32x4 pg = *reinterpret_cast<const f32x4*>(P + 2 * MAT_ELEMS + i);
  f32x4 po = *reinterpret_cast<const f32x4*>(P + 3 * MAT_ELEMS + i);
  f32x4 cc = *reinterpret_cast<const f32x4*>(c + i);
  f32x4 hn, cn;
#pragma unroll
  for (int j = 0; j < 4; ++j) {
    float ig = fast_sigmoid(pi[j]);
    float fg = fast_sigmoid(pf[j]);
    float gg = fast_tanh(pg[j]);
    float og = fast_sigmoid(po[j]);
    float cv = fg * cc[j] + ig * gg;
    cn[j] = cv;
    hn[j] = og * fast_tanh(cv);
  }
  *reinterpret_cast<f32x4*>(out + i) = hn;                 // h_new
  *reinterpret_cast<f32x4*>(out + MAT_ELEMS + i) = cn;     // c_new
}

// ---------- launch ----------

extern "C" void kernel_launch(void* const* d_in, const int* in_sizes, int n_in,
                              void* d_out, int out_size, void* d_ws, size_t ws_size,
                              hipStream_t stream) {
  const float* x = (const float*)d_in[0];
  const float* h = (const float*)d_in[1];
  const float* c = (const float*)d_in[2];
  // d_in[3+3g]=L_g, d_in[4+3g]=R_g, d_in[5+3g]=b_g for g in {ii,hi,if,hf,ig,hg,io,ho}

  // ws layout (68 MB total):
  u16* Lb   = (u16*)d_ws;                       // 8 x 1M bf16  (16 MB)
  u16* xT   = Lb + ((size_t)8 << 20);           // 1M bf16      ( 2 MB)
  u16* hT   = xT + ((size_t)1 << 20);           // 1M bf16      ( 2 MB)
  u16* RT   = hT + ((size_t)1 << 20);           // 8 x 1M bf16  (16 MB)
  u16* Tbuf = RT + ((size_t)8 << 20);           // 8 x 1M bf16  (16 MB)
  float* P  = (float*)(Tbuf + ((size_t)8 << 20)); // 4 x 1M f32 (16 MB)

  P8 lp;
  for (int g = 0; g < 8; ++g) lp.p[g] = (const float*)d_in[3 + 3 * g];
  P10 tp;
  tp.p[0] = x; tp.p[1] = h;
  for (int g = 0; g < 8; ++g) tp.p[2 + g] = (const float*)d_in[4 + 3 * g];
  B8 bp;
  for (int g = 0; g < 8; ++g) bp.b[g] = (const float*)d_in[5 + 3 * g];

  cast8_kernel<<<dim3(1024, 8), 256, 0, stream>>>(lp, Lb);
  transpose_cast_kernel<<<dim3(32, 32, 10), 256, 0, stream>>>(tp, xT);
  gemm_stage1_kernel<<<dim3(64, 8), 256, 0, stream>>>(Lb, xT, hT, Tbuf);
  gemm_stage2_kernel<<<dim3(64, 4), 256, 0, stream>>>(Tbuf, RT, bp, P);
  lstm_cell_kernel<<<1024, 256, 0, stream>>>(P, c, (float*)d_out);
}

// Round 3
// 251.466 us; speedup vs baseline: 1.0260x; 1.0260x over previous
//
#include <hip/hip_runtime.h>
#include <stdint.h>

typedef __bf16 bf16x8 __attribute__((ext_vector_type(8)));
typedef float  f32x4  __attribute__((ext_vector_type(4)));
typedef uint16_t u16;

#define MAT_ELEMS (1024 * 1024)
#define LDK 1024

// ---------- helpers ----------

__device__ __forceinline__ u16 to_bf16(float f) {
  union { float f; uint32_t u; } v; v.f = f;
  uint32_t u = v.u;
  uint32_t r = u + 0x7FFFu + ((u >> 16) & 1u);   // RNE
  return (u16)(r >> 16);
}

__device__ __forceinline__ float bf16_to_f32(u16 b) {
  union { uint32_t u; float f; } v; v.u = ((uint32_t)b) << 16;
  return v.f;
}

__device__ __forceinline__ void gll16(const void* g, void* l) {
  __builtin_amdgcn_global_load_lds(
      (__attribute__((address_space(1))) void*)const_cast<void*>(g),
      (__attribute__((address_space(3))) void*)(l),
      16, 0, 0);
}

__device__ __forceinline__ float fast_sigmoid(float x) {
  x = fminf(fmaxf(x, -30.f), 30.f);
  return 1.0f / (1.0f + __expf(-x));
}

__device__ __forceinline__ float fast_tanh(float x) {
  x = fminf(fmaxf(x, -15.f), 15.f);
  float e = __expf(2.0f * x);
  return (e - 1.0f) / (e + 1.0f);
}

// ---------- prep kernels ----------

struct P8  { const float* p[8]; };
struct P10 { const float* p[10]; };
struct B8  { const float* b[8]; };

__global__ __launch_bounds__(256) void cast8_kernel(P8 s, u16* __restrict__ dst) {
  const float* src = s.p[blockIdx.y];
  u16* d = dst + ((size_t)blockIdx.y << 20);
  int i = (blockIdx.x * 256 + threadIdx.x) * 4;
  f32x4 v = *reinterpret_cast<const f32x4*>(src + i);
  ushort4 o;
  o.x = to_bf16(v[0]); o.y = to_bf16(v[1]);
  o.z = to_bf16(v[2]); o.w = to_bf16(v[3]);
  *reinterpret_cast<ushort4*>(d + i) = o;
}

__global__ __launch_bounds__(256) void transpose_cast_kernel(P10 s, u16* __restrict__ dstbase) {
  __shared__ float tile[32][33];
  const float* src = s.p[blockIdx.z];
  u16* dst = dstbase + ((size_t)blockIdx.z << 20);
  int tx = threadIdx.x & 31;
  int ty = threadIdx.x >> 5;
  int c0 = blockIdx.x * 32;
  int r0 = blockIdx.y * 32;
#pragma unroll
  for (int i = 0; i < 4; ++i)
    tile[ty + i * 8][tx] = src[(size_t)(r0 + ty + i * 8) * 1024 + c0 + tx];
  __syncthreads();
#pragma unroll
  for (int i = 0; i < 4; ++i) {
    int n = c0 + ty + i * 8;
    int k = r0 + tx;
    dst[(size_t)n * 1024 + k] = to_bf16(tile[tx][ty + i * 8]);
  }
}

// ---------- GEMM core: 64x128 tile, BK=32, 4 waves (each 32x64) ----------
// A row-major [1024][1024] bf16; B transposed BT[n][k] bf16.
// MODE 0: out = bf16(acc). MODE 1: out = bf16(acc + bias).

template <int MODE>
__device__ __forceinline__ void gemm64_body(
    const u16* __restrict__ A, const u16* __restrict__ B,
    int row0, int col0,
    u16* __restrict__ out, const float* __restrict__ bias,
    u16* As, u16* Bs)
{
  const int tid  = threadIdx.x;
  const int lane = tid & 63;
  const int w    = tid >> 6;
  const int wr   = w >> 1;            // 0..1 (row half of tile: 32 rows each)
  const int wc   = w & 1;             // 0..1 (col half: 64 cols each)
  const int r16  = lane & 15;
  const int kg   = lane >> 4;

  f32x4 acc[2][4];
#pragma unroll
  for (int m = 0; m < 2; ++m)
#pragma unroll
    for (int n = 0; n < 4; ++n) {
      f32x4 z = {0.f, 0.f, 0.f, 0.f};
      acc[m][n] = z;
    }

  const int srow = tid >> 2;          // 0..63
  const int skk  = (tid & 3) * 8;
  u16* lA  = As + srow * 32 + skk;
  u16* lB0 = Bs + srow * 32 + skk;
  u16* lB1 = Bs + (srow + 64) * 32 + skk;
  const u16* gA  = A + (size_t)(row0 + srow)      * LDK + skk;
  const u16* gB0 = B + (size_t)(col0 + srow)      * LDK + skk;
  const u16* gB1 = B + (size_t)(col0 + srow + 64) * LDK + skk;

  for (int kt = 0; kt < 32; ++kt) {
    __syncthreads();
    gll16(gA  + kt * 32, lA);
    gll16(gB0 + kt * 32, lB0);
    gll16(gB1 + kt * 32, lB1);
    __syncthreads();

    bf16x8 af[2], bfr[4];
#pragma unroll
    for (int m = 0; m < 2; ++m)
      af[m] = *reinterpret_cast<const bf16x8*>(As + (wr * 32 + m * 16 + r16) * 32 + kg * 8);
#pragma unroll
    for (int n = 0; n < 4; ++n)
      bfr[n] = *reinterpret_cast<const bf16x8*>(Bs + (wc * 64 + n * 16 + r16) * 32 + kg * 8);
#pragma unroll
    for (int m = 0; m < 2; ++m)
#pragma unroll
      for (int n = 0; n < 4; ++n)
        acc[m][n] = __builtin_amdgcn_mfma_f32_16x16x32_bf16(af[m], bfr[n], acc[m][n], 0, 0, 0);
  }

  // D layout: col = lane&15, row = (lane>>4)*4 + r   [m89-verified]
#pragma unroll
  for (int m = 0; m < 2; ++m) {
#pragma unroll
    for (int r = 0; r < 4; ++r) {
      int row = row0 + wr * 32 + m * 16 + kg * 4 + r;
#pragma unroll
      for (int n = 0; n < 4; ++n) {
        int col = col0 + wc * 64 + n * 16 + r16;
        size_t idx = (size_t)row * 1024 + col;
        float v = acc[m][n][r];
        if (MODE == 1) v += bias[idx];
        out[idx] = to_bf16(v);
      }
    }
  }
}

// stage 1: T_g = L_g @ {x|h}   (8 GEMMs, K=1024), grid (128, 8)
__global__ __launch_bounds__(256) void gemm_stage1_kernel(
    const u16* __restrict__ Lb, const u16* __restrict__ xT,
    const u16* __restrict__ hT, u16* __restrict__ Tbuf)
{
  __shared__ u16 As[64 * 32];
  __shared__ u16 Bs[128 * 32];
  int g = blockIdx.y;
  const u16* A = Lb + ((size_t)g << 20);
  const u16* B = (g & 1) ? hT : xT;
  int row0 = (blockIdx.x >> 3) * 64;
  int col0 = (blockIdx.x & 7) * 128;
  gemm64_body<0>(A, B, row0, col0, Tbuf + ((size_t)g << 20), nullptr, As, Bs);
}

// stage 2: P_g = T_g @ R_g + b_g   (8 GEMMs, K=1024), grid (128, 8)
__global__ __launch_bounds__(256) void gemm_stage2_kernel(
    const u16* __restrict__ Tbuf, const u16* __restrict__ RT,
    B8 bp, u16* __restrict__ P)
{
  __shared__ u16 As[64 * 32];
  __shared__ u16 Bs[128 * 32];
  int g = blockIdx.y;
  const u16* A = Tbuf + ((size_t)g << 20);
  const u16* B = RT   + ((size_t)g << 20);
  int row0 = (blockIdx.x >> 3) * 64;
  int col0 = (blockIdx.x & 7) * 128;
  gemm64_body<1>(A, B, row0, col0, P + ((size_t)g << 20), bp.b[g], As, Bs);
}

// cell: sums gate pairs, applies nonlinearities
__global__ __launch_bounds__(256) void lstm_cell_kernel(
    const u16* __restrict__ P, const float* __restrict__ c, float* __restrict__ out)
{
  int i = (blockIdx.x * 256 + threadIdx.x) * 4;
  ushort4 pv[8];
#pragma unroll
  for (int g = 0; g < 8; ++g)
    pv[g] = *reinterpret_cast<const ushort4*>(P + (size_t)g * MAT_ELEMS + i);
  f32x4 cc = *reinterpret_cast<const f32x4*>(c + i);
  f32x4 hn, cn;
#pragma unroll
  for (int j = 0; j < 4; ++j) {
    float pi = bf16_to_f32((&pv[0].x)[j]) + bf16_to_f32((&pv[1].x)[j]);
    float pf = bf16_to_f32((&pv[2].x)[j]) + bf16_to_f32((&pv[3].x)[j]);
    float pg = bf16_to_f32((&pv[4].x)[j]) + bf16_to_f32((&pv[5].x)[j]);
    float po = bf16_to_f32((&pv[6].x)[j]) + bf16_to_f32((&pv[7].x)[j]);
    float ig = fast_sigmoid(pi);
    float fg = fast_sigmoid(pf);
    float gg = fast_tanh(pg);
    float og = fast_sigmoid(po);
    float cv = fg * cc[j] + ig * gg;
    cn[j] = cv;
    hn[j] = og * fast_tanh(cv);
  }
  *reinterpret_cast<f32x4*>(out + i) = hn;
  *reinterpret_cast<f32x4*>(out + MAT_ELEMS + i) = cn;
}

// ---------- launch ----------

extern "C" void kernel_launch(void* const* d_in, const int* in_sizes, int n_in,
                              void* d_out, int out_size, void* d_ws, size_t ws_size,
                              hipStream_t stream) {
  const float* x = (const float*)d_in[0];
  const float* h = (const float*)d_in[1];
  const float* c = (const float*)d_in[2];

  // ws layout (68 MB):
  u16* Lb   = (u16*)d_ws;                         // 8 x 1M bf16 (16 MB)
  u16* xT   = Lb + ((size_t)8 << 20);             // 2 MB
  u16* hT   = xT + ((size_t)1 << 20);             // 2 MB
  u16* RT   = hT + ((size_t)1 << 20);             // 16 MB
  u16* Tbuf = RT + ((size_t)8 << 20);             // 16 MB
  u16* P    = Tbuf + ((size_t)8 << 20);           // 8 x 1M bf16 (16 MB)

  P8 lp;
  for (int g = 0; g < 8; ++g) lp.p[g] = (const float*)d_in[3 + 3 * g];
  P10 tp;
  tp.p[0] = x; tp.p[1] = h;
  for (int g = 0; g < 8; ++g) tp.p[2 + g] = (const float*)d_in[4 + 3 * g];
  B8 bp;
  for (int g = 0; g < 8; ++g) bp.b[g] = (const float*)d_in[5 + 3 * g];

  cast8_kernel<<<dim3(1024, 8), 256, 0, stream>>>(lp, Lb);
  transpose_cast_kernel<<<dim3(32, 32, 10), 256, 0, stream>>>(tp, xT);
  gemm_stage1_kernel<<<dim3(128, 8), 256, 0, stream>>>(Lb, xT, hT, Tbuf);
  gemm_stage2_kernel<<<dim3(128, 8), 256, 0, stream>>>(Tbuf, RT, bp, P);
  lstm_cell_kernel<<<1024, 256, 0, stream>>>(P, c, (float*)d_out);
}

// Round 4
// 240.369 us; speedup vs baseline: 1.0733x; 1.0462x over previous
//
#include <hip/hip_runtime.h>
#include <stdint.h>

typedef __bf16 bf16x8 __attribute__((ext_vector_type(8)));
typedef float  f32x4  __attribute__((ext_vector_type(4)));
typedef uint16_t u16;

#define MAT_ELEMS (1024 * 1024)
#define LDK 1024

// ---------- helpers ----------

__device__ __forceinline__ u16 to_bf16(float f) {
  union { float f; uint32_t u; } v; v.f = f;
  uint32_t u = v.u;
  uint32_t r = u + 0x7FFFu + ((u >> 16) & 1u);   // RNE
  return (u16)(r >> 16);
}

__device__ __forceinline__ float bf16_to_f32(u16 b) {
  union { uint32_t u; float f; } v; v.u = ((uint32_t)b) << 16;
  return v.f;
}

__device__ __forceinline__ void gll16(const void* g, void* l) {
  __builtin_amdgcn_global_load_lds(
      (__attribute__((address_space(1))) void*)const_cast<void*>(g),
      (__attribute__((address_space(3))) void*)(l),
      16, 0, 0);
}

__device__ __forceinline__ float fast_sigmoid(float x) {
  x = fminf(fmaxf(x, -30.f), 30.f);
  return 1.0f / (1.0f + __expf(-x));
}

__device__ __forceinline__ float fast_tanh(float x) {
  x = fminf(fmaxf(x, -15.f), 15.f);
  float e = __expf(2.0f * x);
  return (e - 1.0f) / (e + 1.0f);
}

// ---------- prep kernels ----------

struct P8  { const float* p[8]; };
struct P10 { const float* p[10]; };
struct B8  { const float* b[8]; };

__global__ __launch_bounds__(256) void cast8_kernel(P8 s, u16* __restrict__ dst) {
  const float* src = s.p[blockIdx.y];
  u16* d = dst + ((size_t)blockIdx.y << 20);
  int i = (blockIdx.x * 256 + threadIdx.x) * 4;
  f32x4 v = *reinterpret_cast<const f32x4*>(src + i);
  ushort4 o;
  o.x = to_bf16(v[0]); o.y = to_bf16(v[1]);
  o.z = to_bf16(v[2]); o.w = to_bf16(v[3]);
  *reinterpret_cast<ushort4*>(d + i) = o;
}

__global__ __launch_bounds__(256) void transpose_cast_kernel(P10 s, u16* __restrict__ dstbase) {
  __shared__ float tile[32][33];
  const float* src = s.p[blockIdx.z];
  u16* dst = dstbase + ((size_t)blockIdx.z << 20);
  int tx = threadIdx.x & 31;
  int ty = threadIdx.x >> 5;
  int c0 = blockIdx.x * 32;
  int r0 = blockIdx.y * 32;
#pragma unroll
  for (int i = 0; i < 4; ++i)
    tile[ty + i * 8][tx] = src[(size_t)(r0 + ty + i * 8) * 1024 + c0 + tx];
  __syncthreads();
#pragma unroll
  for (int i = 0; i < 4; ++i) {
    int n = c0 + ty + i * 8;
    int k = r0 + tx;
    dst[(size_t)n * 1024 + k] = to_bf16(tile[tx][ty + i * 8]);
  }
}

// ---------- GEMM: 128x128 tile, BK=32, 4 waves, double-buffered LDS ----------
// A row-major [1024][1024] bf16 (K contiguous); B transposed BT[n][k] bf16.
// out = bf16(A @ B^T_tile) — pure epilogue, no bias.

__device__ __forceinline__ void gemm128_dbuf(
    const u16* __restrict__ A, const u16* __restrict__ B,
    int row0, int col0, u16* __restrict__ out,
    u16* As0, u16* As1, u16* Bs0, u16* Bs1)
{
  const int tid  = threadIdx.x;
  const int lane = tid & 63;
  const int w    = tid >> 6;
  const int wr   = w >> 1;            // 0..1: 64-row half
  const int wc   = w & 1;             // 0..1: 64-col half
  const int r16  = lane & 15;
  const int kg   = lane >> 4;         // 0..3

  f32x4 acc[4][4];
#pragma unroll
  for (int m = 0; m < 4; ++m)
#pragma unroll
    for (int n = 0; n < 4; ++n) {
      f32x4 z = {0.f, 0.f, 0.f, 0.f};
      acc[m][n] = z;
    }

  const int srow = tid >> 2;          // 0..63
  const int skk  = (tid & 3) * 8;     // 0,8,16,24

  // stage one K-step (BK=32) into a buffer: LDS dest linear in tid (tid*16B)
  auto stage = [&](u16* Asb, u16* Bsb, int kt) {
    const u16* Ak = A + kt * 32 + skk;
    const u16* Bk = B + kt * 32 + skk;
    gll16(Ak + (size_t)(row0 + srow)      * LDK, Asb + srow * 32 + skk);
    gll16(Ak + (size_t)(row0 + srow + 64) * LDK, Asb + (srow + 64) * 32 + skk);
    gll16(Bk + (size_t)(col0 + srow)      * LDK, Bsb + srow * 32 + skk);
    gll16(Bk + (size_t)(col0 + srow + 64) * LDK, Bsb + (srow + 64) * 32 + skk);
  };

  auto compute = [&](const u16* Asb, const u16* Bsb) {
    bf16x8 af[4], bfr[4];
#pragma unroll
    for (int m = 0; m < 4; ++m)
      af[m] = *reinterpret_cast<const bf16x8*>(Asb + (wr * 64 + m * 16 + r16) * 32 + kg * 8);
#pragma unroll
    for (int n = 0; n < 4; ++n)
      bfr[n] = *reinterpret_cast<const bf16x8*>(Bsb + (wc * 64 + n * 16 + r16) * 32 + kg * 8);
#pragma unroll
    for (int m = 0; m < 4; ++m)
#pragma unroll
      for (int n = 0; n < 4; ++n)
        acc[m][n] = __builtin_amdgcn_mfma_f32_16x16x32_bf16(af[m], bfr[n], acc[m][n], 0, 0, 0);
  };

  // prologue
  stage(As0, Bs0, 0);
  __syncthreads();                     // vmcnt(0) drain by compiler

  // 2-phase main loop, statically unrolled so buffer choice is compile-time
  for (int kt = 0; kt < 32; kt += 2) {
    stage(As1, Bs1, kt + 1);           // prefetch next while computing cur
    compute(As0, Bs0);
    __syncthreads();
    if (kt + 2 < 32) stage(As0, Bs0, kt + 2);
    compute(As1, Bs1);
    __syncthreads();
  }

  // epilogue: D layout col = lane&15, row = (lane>>4)*4 + r  [m89-verified]
#pragma unroll
  for (int m = 0; m < 4; ++m) {
#pragma unroll
    for (int r = 0; r < 4; ++r) {
      int row = row0 + wr * 64 + m * 16 + kg * 4 + r;
#pragma unroll
      for (int n = 0; n < 4; ++n) {
        int col = col0 + wc * 64 + n * 16 + r16;
        out[(size_t)row * 1024 + col] = to_bf16(acc[m][n][r]);
      }
    }
  }
}

// stage 1: T_g = L_g @ {x|h}   (8 GEMMs, K=1024), grid (64, 8)
__global__ __launch_bounds__(256) void gemm_stage1_kernel(
    const u16* __restrict__ Lb, const u16* __restrict__ xT,
    const u16* __restrict__ hT, u16* __restrict__ Tbuf)
{
  __shared__ u16 As0[128 * 32], As1[128 * 32];
  __shared__ u16 Bs0[128 * 32], Bs1[128 * 32];
  int g = blockIdx.y;
  const u16* A = Lb + ((size_t)g << 20);
  const u16* B = (g & 1) ? hT : xT;
  int row0 = (blockIdx.x >> 3) * 128;
  int col0 = (blockIdx.x & 7) * 128;
  gemm128_dbuf(A, B, row0, col0, Tbuf + ((size_t)g << 20), As0, As1, Bs0, Bs1);
}

// stage 2: P_g = T_g @ R_g   (8 GEMMs, K=1024), grid (64, 8); bias added in cell
__global__ __launch_bounds__(256) void gemm_stage2_kernel(
    const u16* __restrict__ Tbuf, const u16* __restrict__ RT,
    u16* __restrict__ P)
{
  __shared__ u16 As0[128 * 32], As1[128 * 32];
  __shared__ u16 Bs0[128 * 32], Bs1[128 * 32];
  int g = blockIdx.y;
  const u16* A = Tbuf + ((size_t)g << 20);
  const u16* B = RT   + ((size_t)g << 20);
  int row0 = (blockIdx.x >> 3) * 128;
  int col0 = (blockIdx.x & 7) * 128;
  gemm128_dbuf(A, B, row0, col0, P + ((size_t)g << 20), As0, As1, Bs0, Bs1);
}

// cell: sums gate pairs + biases, applies nonlinearities
__global__ __launch_bounds__(256) void lstm_cell_kernel(
    const u16* __restrict__ P, B8 bp, const float* __restrict__ c,
    float* __restrict__ out)
{
  int i = (blockIdx.x * 256 + threadIdx.x) * 4;
  ushort4 pv[8];
#pragma unroll
  for (int g = 0; g < 8; ++g)
    pv[g] = *reinterpret_cast<const ushort4*>(P + (size_t)g * MAT_ELEMS + i);
  f32x4 bv[8];
#pragma unroll
  for (int g = 0; g < 8; ++g)
    bv[g] = *reinterpret_cast<const f32x4*>(bp.b[g] + i);
  f32x4 cc = *reinterpret_cast<const f32x4*>(c + i);
  f32x4 hn, cn;
#pragma unroll
  for (int j = 0; j < 4; ++j) {
    float pi = bf16_to_f32((&pv[0].x)[j]) + bf16_to_f32((&pv[1].x)[j]) + bv[0][j] + bv[1][j];
    float pf = bf16_to_f32((&pv[2].x)[j]) + bf16_to_f32((&pv[3].x)[j]) + bv[2][j] + bv[3][j];
    float pg = bf16_to_f32((&pv[4].x)[j]) + bf16_to_f32((&pv[5].x)[j]) + bv[4][j] + bv[5][j];
    float po = bf16_to_f32((&pv[6].x)[j]) + bf16_to_f32((&pv[7].x)[j]) + bv[6][j] + bv[7][j];
    float ig = fast_sigmoid(pi);
    float fg = fast_sigmoid(pf);
    float gg = fast_tanh(pg);
    float og = fast_sigmoid(po);
    float cv = fg * cc[j] + ig * gg;
    cn[j] = cv;
    hn[j] = og * fast_tanh(cv);
  }
  *reinterpret_cast<f32x4*>(out + i) = hn;
  *reinterpret_cast<f32x4*>(out + MAT_ELEMS + i) = cn;
}

// ---------- launch ----------

extern "C" void kernel_launch(void* const* d_in, const int* in_sizes, int n_in,
                              void* d_out, int out_size, void* d_ws, size_t ws_size,
                              hipStream_t stream) {
  const float* x = (const float*)d_in[0];
  const float* h = (const float*)d_in[1];
  const float* c = (const float*)d_in[2];

  // ws layout (68 MB):
  u16* Lb   = (u16*)d_ws;                         // 8 x 1M bf16 (16 MB)
  u16* xT   = Lb + ((size_t)8 << 20);             // 2 MB
  u16* hT   = xT + ((size_t)1 << 20);             // 2 MB
  u16* RT   = hT + ((size_t)1 << 20);             // 16 MB
  u16* Tbuf = RT + ((size_t)8 << 20);             // 16 MB
  u16* P    = Tbuf + ((size_t)8 << 20);           // 8 x 1M bf16 (16 MB)

  P8 lp;
  for (int g = 0; g < 8; ++g) lp.p[g] = (const float*)d_in[3 + 3 * g];
  P10 tp;
  tp.p[0] = x; tp.p[1] = h;
  for (int g = 0; g < 8; ++g) tp.p[2 + g] = (const float*)d_in[4 + 3 * g];
  B8 bp;
  for (int g = 0; g < 8; ++g) bp.b[g] = (const float*)d_in[5 + 3 * g];

  cast8_kernel<<<dim3(1024, 8), 256, 0, stream>>>(lp, Lb);
  transpose_cast_kernel<<<dim3(32, 32, 10), 256, 0, stream>>>(tp, xT);
  gemm_stage1_kernel<<<dim3(64, 8), 256, 0, stream>>>(Lb, xT, hT, Tbuf);
  gemm_stage2_kernel<<<dim3(64, 8), 256, 0, stream>>>(Tbuf, RT, P);
  lstm_cell_kernel<<<1024, 256, 0, stream>>>(P, bp, c, (float*)d_out);
}

// Round 5
// 232.229 us; speedup vs baseline: 1.1110x; 1.0351x over previous
//
#include <hip/hip_runtime.h>
#include <stdint.h>

typedef __bf16 bf16x8 __attribute__((ext_vector_type(8)));
typedef float  f32x4  __attribute__((ext_vector_type(4)));
typedef uint16_t u16;

#define MAT_ELEMS (1024 * 1024)
#define LDK 1024

// ---------- helpers ----------

__device__ __forceinline__ u16 to_bf16(float f) {
  union { float f; uint32_t u; } v; v.f = f;
  uint32_t u = v.u;
  uint32_t r = u + 0x7FFFu + ((u >> 16) & 1u);   // RNE
  return (u16)(r >> 16);
}

__device__ __forceinline__ float bf16_to_f32(u16 b) {
  union { uint32_t u; float f; } v; v.u = ((uint32_t)b) << 16;
  return v.f;
}

__device__ __forceinline__ void gll16(const void* g, void* l) {
  __builtin_amdgcn_global_load_lds(
      (__attribute__((address_space(1))) void*)const_cast<void*>(g),
      (__attribute__((address_space(3))) void*)(l),
      16, 0, 0);
}

__device__ __forceinline__ float fast_sigmoid(float x) {
  x = fminf(fmaxf(x, -30.f), 30.f);
  return 1.0f / (1.0f + __expf(-x));
}

__device__ __forceinline__ float fast_tanh(float x) {
  x = fminf(fmaxf(x, -15.f), 15.f);
  float e = __expf(2.0f * x);
  return (e - 1.0f) / (e + 1.0f);
}

// ---------- prep kernels ----------

struct P8  { const float* p[8]; };
struct P10 { const float* p[10]; };
struct B8  { const float* b[8]; };

__global__ __launch_bounds__(256) void cast8_kernel(P8 s, u16* __restrict__ dst) {
  const float* src = s.p[blockIdx.y];
  u16* d = dst + ((size_t)blockIdx.y << 20);
  int i = (blockIdx.x * 256 + threadIdx.x) * 4;
  f32x4 v = *reinterpret_cast<const f32x4*>(src + i);
  ushort4 o;
  o.x = to_bf16(v[0]); o.y = to_bf16(v[1]);
  o.z = to_bf16(v[2]); o.w = to_bf16(v[3]);
  *reinterpret_cast<ushort4*>(d + i) = o;
}

// transpose+cast 64(src cols) x 32(src rows) tiles; 256B coalesced f32 reads
__global__ __launch_bounds__(256) void transpose_cast_kernel(P10 s, u16* __restrict__ dstbase) {
  __shared__ float tile[32][65];
  const float* src = s.p[blockIdx.z];
  u16* dst = dstbase + ((size_t)blockIdx.z << 20);
  int c0 = blockIdx.x * 64;            // source col block
  int r0 = blockIdx.y * 32;            // source row block
  int cl = threadIdx.x & 63;
  int rg = threadIdx.x >> 6;           // 0..3
#pragma unroll
  for (int i = 0; i < 8; ++i) {
    int r = rg + i * 4;
    tile[r][cl] = src[(size_t)(r0 + r) * 1024 + c0 + cl];
  }
  __syncthreads();
  int kl = threadIdx.x & 31;
  int ng = threadIdx.x >> 5;           // 0..7
#pragma unroll
  for (int i = 0; i < 8; ++i) {
    int n = ng + i * 8;                // 0..63 output row (= source col)
    dst[(size_t)(c0 + n) * 1024 + r0 + kl] = to_bf16(tile[kl][n]);
  }
}

// ---------- GEMM: 128x128 tile, BK=32, 4 waves, double-buffered LDS ----------
// A row-major [1024][1024] bf16 (K contiguous); B transposed BT[n][k] bf16.
// out = bf16(A @ B^T_tile)

__device__ __forceinline__ void gemm128_dbuf(
    const u16* __restrict__ A, const u16* __restrict__ B,
    int row0, int col0, u16* __restrict__ out,
    u16* As0, u16* As1, u16* Bs0, u16* Bs1)
{
  const int tid  = threadIdx.x;
  const int lane = tid & 63;
  const int w    = tid >> 6;
  const int wr   = w >> 1;
  const int wc   = w & 1;
  const int r16  = lane & 15;
  const int kg   = lane >> 4;

  f32x4 acc[4][4];
#pragma unroll
  for (int m = 0; m < 4; ++m)
#pragma unroll
    for (int n = 0; n < 4; ++n) {
      f32x4 z = {0.f, 0.f, 0.f, 0.f};
      acc[m][n] = z;
    }

  const int srow = tid >> 2;
  const int skk  = (tid & 3) * 8;

  auto stage = [&](u16* Asb, u16* Bsb, int kt) {
    const u16* Ak = A + kt * 32 + skk;
    const u16* Bk = B + kt * 32 + skk;
    gll16(Ak + (size_t)(row0 + srow)      * LDK, Asb + srow * 32 + skk);
    gll16(Ak + (size_t)(row0 + srow + 64) * LDK, Asb + (srow + 64) * 32 + skk);
    gll16(Bk + (size_t)(col0 + srow)      * LDK, Bsb + srow * 32 + skk);
    gll16(Bk + (size_t)(col0 + srow + 64) * LDK, Bsb + (srow + 64) * 32 + skk);
  };

  auto compute = [&](const u16* Asb, const u16* Bsb) {
    bf16x8 af[4], bfr[4];
#pragma unroll
    for (int m = 0; m < 4; ++m)
      af[m] = *reinterpret_cast<const bf16x8*>(Asb + (wr * 64 + m * 16 + r16) * 32 + kg * 8);
#pragma unroll
    for (int n = 0; n < 4; ++n)
      bfr[n] = *reinterpret_cast<const bf16x8*>(Bsb + (wc * 64 + n * 16 + r16) * 32 + kg * 8);
#pragma unroll
    for (int m = 0; m < 4; ++m)
#pragma unroll
      for (int n = 0; n < 4; ++n)
        acc[m][n] = __builtin_amdgcn_mfma_f32_16x16x32_bf16(af[m], bfr[n], acc[m][n], 0, 0, 0);
  };

  stage(As0, Bs0, 0);
  __syncthreads();

  for (int kt = 0; kt < 32; kt += 2) {
    stage(As1, Bs1, kt + 1);
    compute(As0, Bs0);
    __syncthreads();
    if (kt + 2 < 32) stage(As0, Bs0, kt + 2);
    compute(As1, Bs1);
    __syncthreads();
  }

  // epilogue: D layout col = lane&15, row = (lane>>4)*4 + r  [m89-verified]
#pragma unroll
  for (int m = 0; m < 4; ++m) {
#pragma unroll
    for (int r = 0; r < 4; ++r) {
      int row = row0 + wr * 64 + m * 16 + kg * 4 + r;
#pragma unroll
      for (int n = 0; n < 4; ++n) {
        int col = col0 + wc * 64 + n * 16 + r16;
        out[(size_t)row * 1024 + col] = to_bf16(acc[m][n][r]);
      }
    }
  }
}

// chunked XCD swizzle (m157, bijective since 512%8==0): XCD j gets one gate's GEMM
__device__ __forceinline__ void swz_decode(int bx, int& g, int& row0, int& col0) {
  int wg = ((bx & 7) << 6) | (bx >> 3);   // (orig%8)*64 + orig/8
  g = wg >> 6;
  int tile = wg & 63;
  row0 = (tile >> 3) * 128;
  col0 = (tile & 7) * 128;
}

// stage 1: T_g = L_g @ {x|h}   (8 GEMMs, K=1024), grid 512
__global__ __launch_bounds__(256) void gemm_stage1_kernel(
    const u16* __restrict__ Lb, const u16* __restrict__ xT,
    const u16* __restrict__ hT, u16* __restrict__ Tbuf)
{
  __shared__ u16 As0[128 * 32], As1[128 * 32];
  __shared__ u16 Bs0[128 * 32], Bs1[128 * 32];
  int g, row0, col0;
  swz_decode(blockIdx.x, g, row0, col0);
  const u16* A = Lb + ((size_t)g << 20);
  const u16* B = (g & 1) ? hT : xT;
  gemm128_dbuf(A, B, row0, col0, Tbuf + ((size_t)g << 20), As0, As1, Bs0, Bs1);
}

// stage 2: P_g = T_g @ R_g   (8 GEMMs, K=1024), grid 512
__global__ __launch_bounds__(256) void gemm_stage2_kernel(
    const u16* __restrict__ Tbuf, const u16* __restrict__ RT,
    u16* __restrict__ P)
{
  __shared__ u16 As0[128 * 32], As1[128 * 32];
  __shared__ u16 Bs0[128 * 32], Bs1[128 * 32];
  int g, row0, col0;
  swz_decode(blockIdx.x, g, row0, col0);
  const u16* A = Tbuf + ((size_t)g << 20);
  const u16* B = RT   + ((size_t)g << 20);
  gemm128_dbuf(A, B, row0, col0, P + ((size_t)g << 20), As0, As1, Bs0, Bs1);
}

// cell: sums gate pairs + biases, applies nonlinearities
__global__ __launch_bounds__(256) void lstm_cell_kernel(
    const u16* __restrict__ P, B8 bp, const float* __restrict__ c,
    float* __restrict__ out)
{
  int i = (blockIdx.x * 256 + threadIdx.x) * 4;
  ushort4 pv[8];
#pragma unroll
  for (int g = 0; g < 8; ++g)
    pv[g] = *reinterpret_cast<const ushort4*>(P + (size_t)g * MAT_ELEMS + i);
  f32x4 bv[8];
#pragma unroll
  for (int g = 0; g < 8; ++g)
    bv[g] = *reinterpret_cast<const f32x4*>(bp.b[g] + i);
  f32x4 cc = *reinterpret_cast<const f32x4*>(c + i);
  f32x4 hn, cn;
#pragma unroll
  for (int j = 0; j < 4; ++j) {
    float pi = bf16_to_f32((&pv[0].x)[j]) + bf16_to_f32((&pv[1].x)[j]) + bv[0][j] + bv[1][j];
    float pf = bf16_to_f32((&pv[2].x)[j]) + bf16_to_f32((&pv[3].x)[j]) + bv[2][j] + bv[3][j];
    float pg = bf16_to_f32((&pv[4].x)[j]) + bf16_to_f32((&pv[5].x)[j]) + bv[4][j] + bv[5][j];
    float po = bf16_to_f32((&pv[6].x)[j]) + bf16_to_f32((&pv[7].x)[j]) + bv[6][j] + bv[7][j];
    float ig = fast_sigmoid(pi);
    float fg = fast_sigmoid(pf);
    float gg = fast_tanh(pg);
    float og = fast_sigmoid(po);
    float cv = fg * cc[j] + ig * gg;
    cn[j] = cv;
    hn[j] = og * fast_tanh(cv);
  }
  *reinterpret_cast<f32x4*>(out + i) = hn;
  *reinterpret_cast<f32x4*>(out + MAT_ELEMS + i) = cn;
}

// ---------- launch ----------

extern "C" void kernel_launch(void* const* d_in, const int* in_sizes, int n_in,
                              void* d_out, int out_size, void* d_ws, size_t ws_size,
                              hipStream_t stream) {
  const float* x = (const float*)d_in[0];
  const float* h = (const float*)d_in[1];
  const float* c = (const float*)d_in[2];

  // ws layout (68 MB):
  u16* Lb   = (u16*)d_ws;                         // 8 x 1M bf16 (16 MB)
  u16* xT   = Lb + ((size_t)8 << 20);             // 2 MB
  u16* hT   = xT + ((size_t)1 << 20);             // 2 MB
  u16* RT   = hT + ((size_t)1 << 20);             // 16 MB
  u16* Tbuf = RT + ((size_t)8 << 20);             // 16 MB
  u16* P    = Tbuf + ((size_t)8 << 20);           // 8 x 1M bf16 (16 MB)

  P8 lp;
  for (int g = 0; g < 8; ++g) lp.p[g] = (const float*)d_in[3 + 3 * g];
  P10 tp;
  tp.p[0] = x; tp.p[1] = h;
  for (int g = 0; g < 8; ++g) tp.p[2 + g] = (const float*)d_in[4 + 3 * g];
  B8 bp;
  for (int g = 0; g < 8; ++g) bp.b[g] = (const float*)d_in[5 + 3 * g];

  cast8_kernel<<<dim3(1024, 8), 256, 0, stream>>>(lp, Lb);
  transpose_cast_kernel<<<dim3(16, 32, 10), 256, 0, stream>>>(tp, xT);
  gemm_stage1_kernel<<<512, 256, 0, stream>>>(Lb, xT, hT, Tbuf);
  gemm_stage2_kernel<<<512, 256, 0, stream>>>(Tbuf, RT, P);
  lstm_cell_kernel<<<1024, 256, 0, stream>>>(P, bp, c, (float*)d_out);
}